// Round 13
// baseline (153.097 us; speedup 1.0000x reference)
//
#include <hip/hip_runtime.h>
#include <cstdint>

#define NB 2
#define NSEQ 2048
#define CDIM 768
#define NH 12
#define HD 64
#define NTOK (NB*NSEQ)        // 4096
#define QKV_COLS (3*CDIM)     // 2304
#define NBLK ((NSEQ/64)*NH*NB) // 768 attn blocks

typedef short bf16x8 __attribute__((ext_vector_type(8)));
typedef short bf16x4 __attribute__((ext_vector_type(4)));
typedef float f32x4  __attribute__((ext_vector_type(4)));
typedef short short4v __attribute__((ext_vector_type(4)));
typedef unsigned int uint4v __attribute__((ext_vector_type(4)));

#define MFMA16(a,b,c) __builtin_amdgcn_mfma_f32_16x16x32_bf16(a,b,c,0,0,0)

__device__ __forceinline__ short f2b(float f) {
    uint32_t u = __builtin_bit_cast(uint32_t, f);
    u += 0x7fffu + ((u >> 16) & 1u);
    return (short)(u >> 16);
}
__device__ __forceinline__ float b2f(short s) {
    return __builtin_bit_cast(float, (uint32_t)((uint32_t)(unsigned short)s << 16));
}
__device__ __forceinline__ unsigned pack2(float a, float b) {
    unsigned ua = __builtin_bit_cast(unsigned, a) + 0x7fffu;
    unsigned ub = __builtin_bit_cast(unsigned, b) + 0x7fffu;
    return __builtin_amdgcn_perm(ub, ua, 0x07060302u);
}
// 2^x on the trans pipe; q is pre-scaled by 0.125*log2(e) so exp2(s)==exp(qk/8).
__device__ __forceinline__ float fexp2(float x) {
#if __has_builtin(__builtin_amdgcn_exp2f)
    return __builtin_amdgcn_exp2f(x);
#else
    return __expf(x * 0.69314718055994531f);
#endif
}
__device__ __forceinline__ void gll16(const short* g, short* l) {
    __builtin_amdgcn_global_load_lds(
        (const __attribute__((address_space(1))) unsigned int*)g,
        (__attribute__((address_space(3))) unsigned int*)l, 16, 0, 0);
}

// ---------------------------------------------------------------------------
// Merged prep (round-11 verbatim): x fp32->bf16, w transposes, mask log2-bias.
// ---------------------------------------------------------------------------
__global__ __launch_bounds__(256) void prep_kernel(
    const float* __restrict__ x, const float* __restrict__ w_qkv,
    const float* __restrict__ w_proj, const int* __restrict__ mask,
    short* __restrict__ xb, short* __restrict__ wqt, short* __restrict__ wpt,
    short* __restrict__ maskb)
{
    __shared__ float tile[32][33];
    const int bid = blockIdx.x, t = threadIdx.x;
    if (bid < 3072) {
        int i = bid * 256 + t;
        float4 v = ((const float4*)x)[i];
        short4v o = { f2b(v.x), f2b(v.y), f2b(v.z), f2b(v.w) };
        ((short4v*)xb)[i] = o;
        return;
    }
    if (bid >= 5376) {
        int i = ((bid - 5376) << 11) + (t << 3);   // 2 blocks x 2048 values
        int4 a = *(const int4*)(mask + i);
        int4 c = *(const int4*)(mask + i + 4);
        const short NEG = (short)0xC680;           // bf16 -16384.0
        short4v o0 = { a.x ? (short)0 : NEG, a.y ? (short)0 : NEG,
                       a.z ? (short)0 : NEG, a.w ? (short)0 : NEG };
        short4v o1 = { c.x ? (short)0 : NEG, c.y ? (short)0 : NEG,
                       c.z ? (short)0 : NEG, c.w ? (short)0 : NEG };
        *(short4v*)(maskb + i) = o0;
        *(short4v*)(maskb + i + 4) = o1;
        return;
    }
    const float* w; short* wt; int K, NC, n0, k0;
    if (bid < 3072 + 1728) {
        int r = bid - 3072;
        w = w_qkv; wt = wqt; K = CDIM; NC = QKV_COLS;
        n0 = (r % 72) * 32; k0 = (r / 72) * 32;
    } else {
        int r = bid - 4800;
        w = w_proj; wt = wpt; K = CDIM; NC = CDIM;
        n0 = (r % 24) * 32; k0 = (r / 24) * 32;
    }
    const int r = t >> 3, c4 = (t & 7) * 4;
    {
        float4 v = *(const float4*)&w[(size_t)(k0 + r) * NC + n0 + c4];
        tile[r][c4 + 0] = v.x; tile[r][c4 + 1] = v.y;
        tile[r][c4 + 2] = v.z; tile[r][c4 + 3] = v.w;
    }
    __syncthreads();
    {
        short4v o = { f2b(tile[c4 + 0][r]), f2b(tile[c4 + 1][r]),
                      f2b(tile[c4 + 2][r]), f2b(tile[c4 + 3][r]) };
        *(short4v*)&wt[(size_t)(n0 + r) * K + k0 + c4] = o;
    }
}

// ---------------------------------------------------------------------------
// GEMM v19: 128m x 64n TILES -> 2x block count for 2x occupancy.
// gemm_qkv at 2.25 blocks/CU is occupancy-bound (round-9 dbuf neutrality =
// latency not covered by barrier restructure => needs TLP). Halving the
// n-tile: qkv 576->1152 blocks (4.5/CU), proj 192->384 (1.5/CU); LDS
// 32->24KB (cap 6/CU), acc[4][2] halves VGPR -> ~18 waves/CU. Per-wave
// MFMA:stage 8:3 vs 16:4 (slightly worse) but aggregate TLP doubles --
// right trade for a latency-bound loop (same reasoning as attn round 4).
// All waves share the 64 A-rows; each wave owns 32 B-rows. 64 | n0 keeps
// the s/h/d0 epilogue derivation exact.
// (Round-12 resubmission: bench infra failed twice; code audit found no
// defect -- staging map algebra, index bijectivity, uniform control flow
// all check out; attn byte-identical to round-11's passing kernel.)
// ---------------------------------------------------------------------------
#define GSTAGE2(K0V, Bf) do {                                                    \
    gll16(ag0 + (K0V), As + (Bf)*2048 + wid*512);                                \
    gll16(bg0 + (K0V), Bs + (Bf)*4096 + wid*512);                                \
    gll16(bg1 + (K0V), Bs + (Bf)*4096 + 2048 + wid*512);                         \
} while (0)

#define GEMM_LOOP() do {                                                         \
    GSTAGE2(0, 0);                                                               \
    __syncthreads();                                                             \
    int buf = 0;                                                                 \
    for (int k0 = 0; k0 < CDIM; k0 += 32) {                                      \
        if (k0 + 32 < CDIM) GSTAGE2(k0 + 32, buf ^ 1);                           \
        __builtin_amdgcn_sched_barrier(0);                                       \
        const short* As_ = As + buf * 2048;                                      \
        const short* Bs_ = Bs + buf * 4096;                                      \
        bf16x8 af[4], bf[2];                                                     \
        _Pragma("unroll")                                                        \
        for (int i = 0; i < 4; ++i)                                              \
            af[i] = *(const bf16x8*)&As_[(i*16 + l16) * 32 + quad*8];            \
        _Pragma("unroll")                                                        \
        for (int j = 0; j < 2; ++j)                                              \
            bf[j] = *(const bf16x8*)&Bs_[(wid*32 + j*16 + l16) * 32 + quad*8];   \
        _Pragma("unroll")                                                        \
        for (int i = 0; i < 4; ++i)                                              \
            _Pragma("unroll")                                                    \
            for (int j = 0; j < 2; ++j)                                          \
                acc[i][j] = MFMA16(af[i], bf[j], acc[i][j]);                     \
        __syncthreads();                                                         \
        buf ^= 1;                                                                \
    }                                                                            \
} while (0)

// ---------------------------------------------------------------------------
// GEMM1. q PRE-SCALED by 0.125*log2(e); V written KEY-PERMUTED (round 11).
// Grid: 1152 blocks, XCD-swizzled (1152 = 8 x 144; m fastest within chunk).
// ---------------------------------------------------------------------------
__global__ __launch_bounds__(256) void gemm_qkv(
    const short* __restrict__ A /*wqt[2304][768]*/,
    const short* __restrict__ B /*xb [4096][768]*/,
    short* __restrict__ qb, short* __restrict__ kb, short* __restrict__ vt)
{
    __shared__ short As[2 * 2048];   // [2][64 x 32]
    __shared__ short Bs[2 * 4096];   // [2][128 x 32]
    const int t = threadIdx.x;
    const int lane = t & 63, wid = t >> 6;
    const int quad = lane >> 4, l16 = lane & 15;
    const int id = blockIdx.x;
    const int lin = (id & 7) * 144 + (id >> 3);
    const int n0 = (lin >> 5) * 64;       // 0..35 -> 0..2240
    const int m0 = (lin & 31) * 128;      // 0..31 -> 0..3968

    const int srow = wid * 16 + (lane >> 2), schunk = (lane & 3) * 8;
    const short* ag0 = A + (size_t)(n0 + srow) * CDIM + schunk;
    const short* bg0 = B + (size_t)(m0 + srow) * CDIM + schunk;
    const short* bg1 = bg0 + (size_t)64 * CDIM;

    f32x4 acc[4][2] = {};
    GEMM_LOOP();

    const int s = n0 / CDIM;
    const int h = (n0 - s * CDIM) >> 6;
    const int b = m0 >> 11;
    const size_t bh = (size_t)(b * NH + h);
    // fold softmax scale AND log2(e) into q: exp(qk/8) == exp2(qk*qsc)
    const float qsc = (s == 0) ? 0.18033688011112042f : 1.0f;
    #pragma unroll
    for (int i = 0; i < 4; ++i) {
        const int d0 = i*16 + quad*4;
        #pragma unroll
        for (int j = 0; j < 2; ++j) {
            int tok = (m0 + wid*32 + j*16 + l16) & (NSEQ - 1);
            if (s < 2) {
                short* dst = (s == 0 ? qb : kb) + (bh * NSEQ + tok) * HD + d0;
                short4v o = { f2b(acc[i][j][0] * qsc), f2b(acc[i][j][1] * qsc),
                              f2b(acc[i][j][2] * qsc), f2b(acc[i][j][3] * qsc) };
                *(short4v*)dst = o;
            } else {
                // key-permute within 64-group: [g][h][c2c1c0][r1r0] ->
                // [g][c2c1c0][h][r1r0]
                int t6 = tok & 63;
                int tokp = (tok & ~63) | ((t6 & 28) << 1)
                         | ((t6 & 32) >> 3) | (t6 & 3);
                short* dst = vt + (bh * HD + d0) * NSEQ + tokp;
                #pragma unroll
                for (int r = 0; r < 4; ++r)
                    dst[(size_t)r * NSEQ] = f2b(acc[i][j][r]);
            }
        }
    }
}

// ---------------------------------------------------------------------------
// Flash attention v18 (byte-identical to round 11's HW-verified kernel):
// 2x2 hybrid split, 3 blocks/CU, counted-vmcnt barriers, setprio around PV,
// single-b128 PV reads via key-permuted V.
// ---------------------------------------------------------------------------
#define STAGE_K(KT, BUF) do {                                                    \
    short* kb_ = (BUF);                                                          \
    _Pragma("unroll")                                                            \
    for (int j = 0; j < 4; ++j)                                                  \
        gll16(kp + (size_t)((KT) + rK[j]) * HD + cK[j]*8,                        \
              kb_ + wid*2048 + j*512);                                           \
} while (0)

#define STAGE_V(KT) do {                                                         \
    _Pragma("unroll")                                                            \
    for (int j = 0; j < 4; ++j)                                                  \
        gll16(vp + (size_t)dV[j] * NSEQ + (KT) + cV[j]*8,                        \
              Vb + wid*2048 + j*512);                                            \
} while (0)

#define QKBODY(KT, KBUF) do {                                                    \
    const short* KsB_ = (KBUF) + kg*4096;                                        \
    _Pragma("unroll")                                                            \
    for (int ks = 0; ks < 2; ++ks) {                                             \
        short4v mi0_ = *(const short4v*)&Msk[(KT) + kg*64 + ks*16 + qrow4];      \
        short4v mi1_ = *(const short4v*)&Msk[(KT) + kg*64 + 32 + ks*16 + qrow4]; \
        const int kro_ = (ks*16 + l16) * 64;                                     \
        bf16x8 kf00_ = *(const bf16x8*)&KsB_[kro_ + kc0];                        \
        bf16x8 kf01_ = *(const bf16x8*)&KsB_[kro_ + kc1];                        \
        bf16x8 kf10_ = *(const bf16x8*)&KsB_[2048 + kro_ + kc0];                 \
        bf16x8 kf11_ = *(const bf16x8*)&KsB_[2048 + kro_ + kc1];                 \
        f32x4 m0v_ = { b2f(mi0_[0]), b2f(mi0_[1]),                               \
                       b2f(mi0_[2]), b2f(mi0_[3]) };                             \
        f32x4 m1v_ = { b2f(mi1_[0]), b2f(mi1_[1]),                               \
                       b2f(mi1_[2]), b2f(mi1_[3]) };                             \
        _Pragma("unroll")                                                        \
        for (int jq = 0; jq < 2; ++jq) {                                         \
            f32x4 s0_ = m0v_, s1_ = m1v_;                                        \
            s0_ = MFMA16(kf00_, qf[jq][0], s0_);                                 \
            s0_ = MFMA16(kf01_, qf[jq][1], s0_);                                 \
            s1_ = MFMA16(kf10_, qf[jq][0], s1_);                                 \
            s1_ = MFMA16(kf11_, qf[jq][1], s1_);                                 \
            float e0 = fexp2(s0_[0]);                                            \
            float e1 = fexp2(s0_[1]);                                            \
            float e2 = fexp2(s0_[2]);                                            \
            float e3 = fexp2(s0_[3]);                                            \
            float f0 = fexp2(s1_[0]);                                            \
            float f1 = fexp2(s1_[1]);                                            \
            float f2 = fexp2(s1_[2]);                                            \
            float f3 = fexp2(s1_[3]);                                            \
            uint4v pk_ = { pack2(e0, e1), pack2(e2, e3),                         \
                           pack2(f0, f1), pack2(f2, f3) };                       \
            pb[jq][ks] = __builtin_bit_cast(bf16x8, pk_);                        \
        }                                                                        \
    }                                                                            \
} while (0)

#define PVBODY() do {                                                            \
    _Pragma("unroll")                                                            \
    for (int ks = 0; ks < 2; ++ks) {                                             \
        lacc[0] = MFMA16(onesv, pb[0][ks], lacc[0]);                             \
        lacc[1] = MFMA16(onesv, pb[1][ks], lacc[1]);                             \
    }                                                                            \
    _Pragma("unroll")                                                            \
    for (int it = 0; it < 4; ++it) {                                             \
        const int vrow_ = (it*16 + l16) * 128;                                   \
        _Pragma("unroll")                                                        \
        for (int ks = 0; ks < 2; ++ks) {                                         \
            bf16x8 vf_ = *(const bf16x8*)&Vb[vrow_ +                             \
                (((kg*8 + ks*4 + quad) ^ l16) << 3)];                            \
            o_acc[0][it] = MFMA16(vf_, pb[0][ks], o_acc[0][it]);                 \
            o_acc[1][it] = MFMA16(vf_, pb[1][ks], o_acc[1][it]);                 \
        }                                                                        \
    }                                                                            \
} while (0)

#define WAITV_BAR() do {                                                         \
    asm volatile("s_waitcnt vmcnt(4)" ::: "memory");                             \
    __builtin_amdgcn_sched_barrier(0);                                           \
    __builtin_amdgcn_s_barrier();                                                \
} while (0)

#define WAITK_BAR() do {                                                         \
    asm volatile("s_waitcnt vmcnt(0)" ::: "memory");                             \
    __builtin_amdgcn_sched_barrier(0);                                           \
    __builtin_amdgcn_s_barrier();                                                \
} while (0)

__global__ __launch_bounds__(256, 3) void attn_kernel(
    const short* __restrict__ qb, const short* __restrict__ kb,
    const short* __restrict__ vt, const short* __restrict__ maskb,
    short* __restrict__ ao)
{
    __shared__ __align__(16) short Kb[2][8192];   // K tiles [128][64], dbuf
    __shared__ __align__(16) short Vb[8192];      // V tile  [64][128], single
    __shared__ __align__(16) short Msk[2048];     // bf16 log2-bias, this b

    const int t = threadIdx.x;
    const int lane = t & 63, wid = t >> 6;
    const int quad = lane >> 4, l16 = lane & 15;
    const int qg = wid >> 1, kg = wid & 1;        // 2x2 hybrid split
    // XCD swizzle: XCD = id%8 owns bh in {xcd, xcd+8, xcd+16}
    const int id = blockIdx.x;
    const int idx = id >> 3;
    const int bh = (id & 7) + ((idx % 3) << 3);
    const int q0 = (idx / 3) << 6;
    const int b = bh / NH, h = bh - b * NH;
    const size_t hoff = (size_t)bh * NSEQ * HD;
    const short* qp = qb + hoff;     // [N][64]  (q pre-scaled by 0.125*log2e)
    const short* kp = kb + hoff;     // [N][64]
    const short* vp = vt + hoff;     // [64][N]  (keys permuted within 64)
    const int qrow4 = quad * 4;

    int rK[4], cK[4], dV[4], cV[4];
    #pragma unroll
    for (int j = 0; j < 4; ++j) {
        int o = wid * 4096 + j * 1024 + lane * 16;
        rK[j] = o >> 7;
        cK[j] = ((o >> 4) & 7) ^ (rK[j] & 7);
        dV[j] = o >> 8;
        cV[j] = ((o >> 4) & 15) ^ (dV[j] & 15);
    }
    const int r7 = l16 & 7;
    const int kc0 = ((quad     ^ r7) << 3);
    const int kc1 = (((quad+4) ^ r7) << 3);

    // Wave's 32 q rows: q0 + qg*32 + jq*16 + l16
    bf16x8 qf[2][2];
    {
        const short* qr = qp + (size_t)(q0 + qg*32 + l16) * HD + quad*8;
        qf[0][0] = *(const bf16x8*)qr;
        qf[0][1] = *(const bf16x8*)(qr + 32);
        qf[1][0] = *(const bf16x8*)(qr + 16*HD);
        qf[1][1] = *(const bf16x8*)(qr + 16*HD + 32);
    }

    const short one_ = (short)0x3F80;             // bf16 1.0
    const bf16x8 onesv = { one_, one_, one_, one_, one_, one_, one_, one_ };

    f32x4 o_acc[2][4] = {};
    f32x4 lacc[2] = {};
    bf16x8 pb[2][2];

    // Prologue: K tile 0 + mask row; __syncthreads drains vmcnt(0).
    STAGE_K(0, Kb[0]);
    gll16(maskb + b * NSEQ + t * 8, Msk + wid * 512);
    __syncthreads();

    for (int kt = 0; kt < NSEQ; kt += 256) {
        STAGE_V(kt);
        __builtin_amdgcn_sched_barrier(0);
        STAGE_K(kt + 128, Kb[1]);
        __builtin_amdgcn_sched_barrier(0);
        QKBODY(kt, Kb[0]);
        WAITV_BAR();              // A: V(kt) visible; K(kt+128) floats
        __builtin_amdgcn_s_setprio(1);
        PVBODY();
        __builtin_amdgcn_s_setprio(0);
        WAITK_BAR();              // B: K(kt+128) visible; Vb free

        STAGE_V(kt + 128);
        __builtin_amdgcn_sched_barrier(0);
        STAGE_K((kt + 256) & (NSEQ - 1), Kb[0]);
        __builtin_amdgcn_sched_barrier(0);
        QKBODY(kt + 128, Kb[1]);
        WAITV_BAR();              // A'
        __builtin_amdgcn_s_setprio(1);
        PVBODY();
        __builtin_amdgcn_s_setprio(0);
        WAITK_BAR();              // B'
    }

    // Epilogue: combine kg=0/kg=1 partials (disjoint key halves) via LDS.
    // Barrier B' carried vmcnt(0) -> wraparound staging landed; Kb is free.
    f32x4* red = (f32x4*)Kb;
    const int rbase = (qg*64 + lane) * 9;
    if (kg == 1) {
        #pragma unroll
        for (int jq = 0; jq < 2; ++jq)
            #pragma unroll
            for (int it = 0; it < 4; ++it)
                red[rbase + jq*4 + it] = o_acc[jq][it];
        f32x4 lv = { lacc[0][0], lacc[1][0], 0.f, 0.f };
        red[rbase + 8] = lv;
    }
    __syncthreads();
    if (kg == 0) {
        f32x4 lv = red[rbase + 8];
        const float inv0 = 1.0f / (lacc[0][0] + lv[0]);
        const float inv1 = 1.0f / (lacc[1][0] + lv[1]);
        #pragma unroll
        for (int jq = 0; jq < 2; ++jq) {
            const float inv = jq ? inv1 : inv0;
            const int tok = b * NSEQ + q0 + qg*32 + jq*16 + l16;
            short* dst = ao + (size_t)tok * CDIM + h * HD + qrow4;
            #pragma unroll
            for (int it = 0; it < 4; ++it) {
                f32x4 o_ = o_acc[jq][it];
                f32x4 r_ = red[rbase + jq*4 + it];
                short4v o = { f2b((o_[0] + r_[0]) * inv),
                              f2b((o_[1] + r_[1]) * inv),
                              f2b((o_[2] + r_[2]) * inv),
                              f2b((o_[3] + r_[3]) * inv) };
                *(short4v*)(dst + it*16) = o;
            }
        }
    }
}

// ---------------------------------------------------------------------------
// GEMM2: 128m x 64n tiles, 384 blocks (1.5/CU vs 0.75), XCD-swizzled
// (384 = 8 x 48; m fastest within chunk).
// ---------------------------------------------------------------------------
__global__ __launch_bounds__(256) void gemm_proj(
    const short* __restrict__ A /*wpt[768][768]*/,
    const short* __restrict__ B /*ao [4096][768]*/,
    const float* __restrict__ bias, float* __restrict__ out)
{
    __shared__ short As[2 * 2048];   // [2][64 x 32]
    __shared__ short Bs[2 * 4096];   // [2][128 x 32]
    const int t = threadIdx.x;
    const int lane = t & 63, wid = t >> 6;
    const int quad = lane >> 4, l16 = lane & 15;
    const int id = blockIdx.x;
    const int lin = (id & 7) * 48 + (id >> 3);
    const int n0 = (lin >> 5) * 64;       // 0..11 -> 0..704
    const int m0 = (lin & 31) * 128;      // 0..31 -> 0..3968

    const int srow = wid * 16 + (lane >> 2), schunk = (lane & 3) * 8;
    const short* ag0 = A + (size_t)(n0 + srow) * CDIM + schunk;
    const short* bg0 = B + (size_t)(m0 + srow) * CDIM + schunk;
    const short* bg1 = bg0 + (size_t)64 * CDIM;

    f32x4 acc[4][2] = {};
    GEMM_LOOP();

    #pragma unroll
    for (int i = 0; i < 4; ++i) {
        int col0 = n0 + i*16 + quad*4;
        float4 bias4 = *(const float4*)&bias[col0];
        #pragma unroll
        for (int j = 0; j < 2; ++j) {
            int tok = m0 + wid*32 + j*16 + l16;
            float4 o = { acc[i][j][0] + bias4.x, acc[i][j][1] + bias4.y,
                         acc[i][j][2] + bias4.z, acc[i][j][3] + bias4.w };
            *(float4*)(out + (size_t)tok * CDIM + col0) = o;
        }
    }
}

extern "C" void kernel_launch(void* const* d_in, const int* in_sizes, int n_in,
                              void* d_out, int out_size, void* d_ws, size_t ws_size,
                              hipStream_t stream)
{
    const float* x      = (const float*)d_in[0];
    const int*   mask   = (const int*)d_in[1];
    const float* w_qkv  = (const float*)d_in[2];
    const float* w_proj = (const float*)d_in[3];
    const float* b_proj = (const float*)d_in[4];
    float* out = (float*)d_out;

    const size_t SZ = (size_t)NTOK * CDIM;       // 3,145,728
    short* xb  = (short*)d_ws;                   // [4096][768]
    short* wqt = xb  + SZ;                       // [2304][768]
    short* wpt = wqt + (size_t)QKV_COLS * CDIM;  // [768][768]
    short* qb  = wpt + (size_t)CDIM * CDIM;      // [BH][N][64]  (pre-scaled q)
    short* kb  = qb  + SZ;                       // [BH][N][64]
    short* vt  = kb  + SZ;                       // [BH][64][N]  (key-permuted)
    short* ao  = vt  + SZ;                       // [4096][768]
    short* maskb = ao + SZ;                      // [B][N] bf16 log2-bias

    dim3 blk(256);
    prep_kernel<<<dim3(5378), blk, 0, stream>>>(x, w_qkv, w_proj, mask,
                                                xb, wqt, wpt, maskb);
    gemm_qkv<<<dim3(1152), blk, 0, stream>>>(wqt, xb, qb, kb, vt);
    attn_kernel<<<dim3(NBLK), blk, 0, stream>>>(qb, kb, vt, maskb, ao);
    gemm_proj<<<dim3(384), blk, 0, stream>>>(wpt, ao, b_proj, out);
}

// Round 14
// 149.988 us; speedup vs baseline: 1.0207x; 1.0207x over previous
//
#include <hip/hip_runtime.h>
#include <cstdint>

#define NB 2
#define NSEQ 2048
#define CDIM 768
#define NH 12
#define HD 64
#define NTOK (NB*NSEQ)        // 4096
#define QKV_COLS (3*CDIM)     // 2304
#define NBLK ((NSEQ/64)*NH*NB) // 768 attn blocks

typedef short bf16x8 __attribute__((ext_vector_type(8)));
typedef short bf16x4 __attribute__((ext_vector_type(4)));
typedef float f32x4  __attribute__((ext_vector_type(4)));
typedef short short4v __attribute__((ext_vector_type(4)));
typedef unsigned int uint4v __attribute__((ext_vector_type(4)));

#define MFMA16(a,b,c) __builtin_amdgcn_mfma_f32_16x16x32_bf16(a,b,c,0,0,0)

__device__ __forceinline__ short f2b(float f) {
    uint32_t u = __builtin_bit_cast(uint32_t, f);
    u += 0x7fffu + ((u >> 16) & 1u);
    return (short)(u >> 16);
}
__device__ __forceinline__ float b2f(short s) {
    return __builtin_bit_cast(float, (uint32_t)((uint32_t)(unsigned short)s << 16));
}
__device__ __forceinline__ unsigned pack2(float a, float b) {
    unsigned ua = __builtin_bit_cast(unsigned, a) + 0x7fffu;
    unsigned ub = __builtin_bit_cast(unsigned, b) + 0x7fffu;
    return __builtin_amdgcn_perm(ub, ua, 0x07060302u);
}
// 2^x on the trans pipe; q is pre-scaled by 0.125*log2(e) so exp2(s)==exp(qk/8).
__device__ __forceinline__ float fexp2(float x) {
#if __has_builtin(__builtin_amdgcn_exp2f)
    return __builtin_amdgcn_exp2f(x);
#else
    return __expf(x * 0.69314718055994531f);
#endif
}
__device__ __forceinline__ void gll16(const short* g, short* l) {
    __builtin_amdgcn_global_load_lds(
        (const __attribute__((address_space(1))) unsigned int*)g,
        (__attribute__((address_space(3))) unsigned int*)l, 16, 0, 0);
}

// ---------------------------------------------------------------------------
// Merged prep: x fp32->bf16 (blocks 0..3071), w_qkv transpose (..4799),
// w_proj transpose (..5375), mask int->bf16 LOG2-BIAS (5376..5377).
// ---------------------------------------------------------------------------
__global__ __launch_bounds__(256) void prep_kernel(
    const float* __restrict__ x, const float* __restrict__ w_qkv,
    const float* __restrict__ w_proj, const int* __restrict__ mask,
    short* __restrict__ xb, short* __restrict__ wqt, short* __restrict__ wpt,
    short* __restrict__ maskb)
{
    __shared__ float tile[32][33];
    const int bid = blockIdx.x, t = threadIdx.x;
    if (bid < 3072) {
        int i = bid * 256 + t;
        float4 v = ((const float4*)x)[i];
        short4v o = { f2b(v.x), f2b(v.y), f2b(v.z), f2b(v.w) };
        ((short4v*)xb)[i] = o;
        return;
    }
    if (bid >= 5376) {
        int i = ((bid - 5376) << 11) + (t << 3);   // 2 blocks x 2048 values
        int4 a = *(const int4*)(mask + i);
        int4 c = *(const int4*)(mask + i + 4);
        const short NEG = (short)0xC680;           // bf16 -16384.0
        short4v o0 = { a.x ? (short)0 : NEG, a.y ? (short)0 : NEG,
                       a.z ? (short)0 : NEG, a.w ? (short)0 : NEG };
        short4v o1 = { c.x ? (short)0 : NEG, c.y ? (short)0 : NEG,
                       c.z ? (short)0 : NEG, c.w ? (short)0 : NEG };
        *(short4v*)(maskb + i) = o0;
        *(short4v*)(maskb + i + 4) = o1;
        return;
    }
    const float* w; short* wt; int K, NC, n0, k0;
    if (bid < 3072 + 1728) {
        int r = bid - 3072;
        w = w_qkv; wt = wqt; K = CDIM; NC = QKV_COLS;
        n0 = (r % 72) * 32; k0 = (r / 72) * 32;
    } else {
        int r = bid - 4800;
        w = w_proj; wt = wpt; K = CDIM; NC = CDIM;
        n0 = (r % 24) * 32; k0 = (r / 24) * 32;
    }
    const int r = t >> 3, c4 = (t & 7) * 4;
    {
        float4 v = *(const float4*)&w[(size_t)(k0 + r) * NC + n0 + c4];
        tile[r][c4 + 0] = v.x; tile[r][c4 + 1] = v.y;
        tile[r][c4 + 2] = v.z; tile[r][c4 + 3] = v.w;
    }
    __syncthreads();
    {
        short4v o = { f2b(tile[c4 + 0][r]), f2b(tile[c4 + 1][r]),
                      f2b(tile[c4 + 2][r]), f2b(tile[c4 + 3][r]) };
        *(short4v*)&wt[(size_t)(n0 + r) * K + k0 + c4] = o;
    }
}

// ---------------------------------------------------------------------------
// GEMM K-loop (HW-verified best config, round 11): 128x128 tiles, double-
// buffered staging, one barrier per K-step, XCD-swizzled 1-D grid (T1).
// Round-13's 128x64 tile (2x blocks/CU) was NEUTRAL -> GEMMs are at their
// small-shape floor; this is the best-measured configuration.
// ---------------------------------------------------------------------------
#define GSTAGE(K0V, B) do {                                                      \
    gll16(ag0 + (K0V), As + (B)*4096 + (wid*16)*32);                             \
    gll16(ag1 + (K0V), As + (B)*4096 + (wid*16 + 64)*32);                        \
    gll16(bg0 + (K0V), Bs + (B)*4096 + (wid*16)*32);                             \
    gll16(bg1 + (K0V), Bs + (B)*4096 + (wid*16 + 64)*32);                        \
} while (0)

// ---------------------------------------------------------------------------
// GEMM1. Epilogue: q PRE-SCALED by 0.125*log2(e) (exp2-fold). V is written
// KEY-PERMUTED within each 64-group: key = g*64+h*32+c*4+r -> key' =
// g*64+c*8+h*4+r, so attn's PV A-fragment (keys {k0..k0+3, k0+32..k0+35})
// becomes 8 CONTIGUOUS bf16 -> single ds_read_b128, no shuffles.
// Grid: 576 blocks, XCD-swizzled (576 = 8 x 72; m fastest within chunk).
// ---------------------------------------------------------------------------
__global__ __launch_bounds__(256) void gemm_qkv(
    const short* __restrict__ A /*wqt[2304][768]*/,
    const short* __restrict__ B /*xb [4096][768]*/,
    short* __restrict__ qb, short* __restrict__ kb, short* __restrict__ vt)
{
    __shared__ short As[2 * 4096];
    __shared__ short Bs[2 * 4096];
    const int t = threadIdx.x;
    const int lane = t & 63, wid = t >> 6;
    const int quad = lane >> 4, l16 = lane & 15;
    const int wA = wid >> 1, wB = wid & 1;
    // XCD swizzle: 576 = 8 XCDs x 72; within a chunk m varies fastest.
    const int id = blockIdx.x;
    const int lin = (id & 7) * 72 + (id >> 3);
    const int n0 = (lin >> 5) * 128;      // 0..17
    const int m0 = (lin & 31) * 128;      // 0..31

    const int srow = wid * 16 + (lane >> 2), schunk = (lane & 3) * 8;
    const short* ag0 = A + (size_t)(n0 + srow) * CDIM + schunk;
    const short* ag1 = ag0 + (size_t)64 * CDIM;
    const short* bg0 = B + (size_t)(m0 + srow) * CDIM + schunk;
    const short* bg1 = bg0 + (size_t)64 * CDIM;

    f32x4 acc[4][4] = {};
    GSTAGE(0, 0);
    __syncthreads();
    int buf = 0;
    for (int k0 = 0; k0 < CDIM; k0 += 32) {
        if (k0 + 32 < CDIM) GSTAGE(k0 + 32, buf ^ 1);
        __builtin_amdgcn_sched_barrier(0);
        const short* As_ = As + buf * 4096;
        const short* Bs_ = Bs + buf * 4096;
        bf16x8 af[4], bf[4];
        #pragma unroll
        for (int i = 0; i < 4; ++i)
            af[i] = *(const bf16x8*)&As_[(wA*64 + i*16 + l16) * 32 + quad*8];
        #pragma unroll
        for (int j = 0; j < 4; ++j)
            bf[j] = *(const bf16x8*)&Bs_[(wB*64 + j*16 + l16) * 32 + quad*8];
        #pragma unroll
        for (int i = 0; i < 4; ++i)
            #pragma unroll
            for (int j = 0; j < 4; ++j)
                acc[i][j] = MFMA16(af[i], bf[j], acc[i][j]);
        __syncthreads();          // stage(next) had the whole MFMA phase
        buf ^= 1;
    }

    const int colbase = n0 + wA * 64;
    const int s = colbase / CDIM;
    const int h = (colbase - s * CDIM) >> 6;
    const int b = m0 >> 11;
    const size_t bh = (size_t)(b * NH + h);
    // fold softmax scale AND log2(e) into q: exp(qk/8) == exp2(qk*qsc)
    const float qsc = (s == 0) ? 0.18033688011112042f : 1.0f;
    #pragma unroll
    for (int i = 0; i < 4; ++i) {
        const int d0 = i*16 + quad*4;
        #pragma unroll
        for (int j = 0; j < 4; ++j) {
            int tok = (m0 + wB*64 + j*16 + l16) & (NSEQ - 1);
            if (s < 2) {
                short* dst = (s == 0 ? qb : kb) + (bh * NSEQ + tok) * HD + d0;
                short4v o = { f2b(acc[i][j][0] * qsc), f2b(acc[i][j][1] * qsc),
                              f2b(acc[i][j][2] * qsc), f2b(acc[i][j][3] * qsc) };
                *(short4v*)dst = o;
            } else {
                // key-permute within 64-group: [g][h][c2c1c0][r1r0] ->
                // [g][c2c1c0][h][r1r0]
                int t6 = tok & 63;
                int tokp = (tok & ~63) | ((t6 & 28) << 1)
                         | ((t6 & 32) >> 3) | (t6 & 3);
                short* dst = vt + (bh * HD + d0) * NSEQ + tokp;
                #pragma unroll
                for (int r = 0; r < 4; ++r)
                    dst[(size_t)r * NSEQ] = f2b(acc[i][j][r]);
            }
        }
    }
}

// ---------------------------------------------------------------------------
// Flash attention v18 (HW-verified, round 11): 2x2 hybrid split, 3 blocks/CU,
// counted-vmcnt barriers, setprio around PV, single-b128 PV reads via
// key-permuted V. Session ladder: 59.5 (v8) -> ~41us here via occupancy fix
// (q-split/hybrid), softmax VALU cut (exp2-fold + mask-as-MFMA-C-init +
// ones-MFMA l-sum), counted vmcnt, V key-permutation.
// ---------------------------------------------------------------------------
#define STAGE_K(KT, BUF) do {                                                    \
    short* kb_ = (BUF);                                                          \
    _Pragma("unroll")                                                            \
    for (int j = 0; j < 4; ++j)                                                  \
        gll16(kp + (size_t)((KT) + rK[j]) * HD + cK[j]*8,                        \
              kb_ + wid*2048 + j*512);                                           \
} while (0)

#define STAGE_V(KT) do {                                                         \
    _Pragma("unroll")                                                            \
    for (int j = 0; j < 4; ++j)                                                  \
        gll16(vp + (size_t)dV[j] * NSEQ + (KT) + cV[j]*8,                        \
              Vb + wid*2048 + j*512);                                            \
} while (0)

#define QKBODY(KT, KBUF) do {                                                    \
    const short* KsB_ = (KBUF) + kg*4096;                                        \
    _Pragma("unroll")                                                            \
    for (int ks = 0; ks < 2; ++ks) {                                             \
        short4v mi0_ = *(const short4v*)&Msk[(KT) + kg*64 + ks*16 + qrow4];      \
        short4v mi1_ = *(const short4v*)&Msk[(KT) + kg*64 + 32 + ks*16 + qrow4]; \
        const int kro_ = (ks*16 + l16) * 64;                                     \
        bf16x8 kf00_ = *(const bf16x8*)&KsB_[kro_ + kc0];                        \
        bf16x8 kf01_ = *(const bf16x8*)&KsB_[kro_ + kc1];                        \
        bf16x8 kf10_ = *(const bf16x8*)&KsB_[2048 + kro_ + kc0];                 \
        bf16x8 kf11_ = *(const bf16x8*)&KsB_[2048 + kro_ + kc1];                 \
        f32x4 m0v_ = { b2f(mi0_[0]), b2f(mi0_[1]),                               \
                       b2f(mi0_[2]), b2f(mi0_[3]) };                             \
        f32x4 m1v_ = { b2f(mi1_[0]), b2f(mi1_[1]),                               \
                       b2f(mi1_[2]), b2f(mi1_[3]) };                             \
        _Pragma("unroll")                                                        \
        for (int jq = 0; jq < 2; ++jq) {                                         \
            f32x4 s0_ = m0v_, s1_ = m1v_;                                        \
            s0_ = MFMA16(kf00_, qf[jq][0], s0_);                                 \
            s0_ = MFMA16(kf01_, qf[jq][1], s0_);                                 \
            s1_ = MFMA16(kf10_, qf[jq][0], s1_);                                 \
            s1_ = MFMA16(kf11_, qf[jq][1], s1_);                                 \
            float e0 = fexp2(s0_[0]);                                            \
            float e1 = fexp2(s0_[1]);                                            \
            float e2 = fexp2(s0_[2]);                                            \
            float e3 = fexp2(s0_[3]);                                            \
            float f0 = fexp2(s1_[0]);                                            \
            float f1 = fexp2(s1_[1]);                                            \
            float f2 = fexp2(s1_[2]);                                            \
            float f3 = fexp2(s1_[3]);                                            \
            uint4v pk_ = { pack2(e0, e1), pack2(e2, e3),                         \
                           pack2(f0, f1), pack2(f2, f3) };                       \
            pb[jq][ks] = __builtin_bit_cast(bf16x8, pk_);                        \
        }                                                                        \
    }                                                                            \
} while (0)

#define PVBODY() do {                                                            \
    _Pragma("unroll")                                                            \
    for (int ks = 0; ks < 2; ++ks) {                                             \
        lacc[0] = MFMA16(onesv, pb[0][ks], lacc[0]);                             \
        lacc[1] = MFMA16(onesv, pb[1][ks], lacc[1]);                             \
    }                                                                            \
    _Pragma("unroll")                                                            \
    for (int it = 0; it < 4; ++it) {                                             \
        const int vrow_ = (it*16 + l16) * 128;                                   \
        _Pragma("unroll")                                                        \
        for (int ks = 0; ks < 2; ++ks) {                                         \
            bf16x8 vf_ = *(const bf16x8*)&Vb[vrow_ +                             \
                (((kg*8 + ks*4 + quad) ^ l16) << 3)];                            \
            o_acc[0][it] = MFMA16(vf_, pb[0][ks], o_acc[0][it]);                 \
            o_acc[1][it] = MFMA16(vf_, pb[1][ks], o_acc[1][it]);                 \
        }                                                                        \
    }                                                                            \
} while (0)

#define WAITV_BAR() do {                                                         \
    asm volatile("s_waitcnt vmcnt(4)" ::: "memory");                             \
    __builtin_amdgcn_sched_barrier(0);                                           \
    __builtin_amdgcn_s_barrier();                                                \
} while (0)

#define WAITK_BAR() do {                                                         \
    asm volatile("s_waitcnt vmcnt(0)" ::: "memory");                             \
    __builtin_amdgcn_sched_barrier(0);                                           \
    __builtin_amdgcn_s_barrier();                                                \
} while (0)

__global__ __launch_bounds__(256, 3) void attn_kernel(
    const short* __restrict__ qb, const short* __restrict__ kb,
    const short* __restrict__ vt, const short* __restrict__ maskb,
    short* __restrict__ ao)
{
    __shared__ __align__(16) short Kb[2][8192];   // K tiles [128][64], dbuf
    __shared__ __align__(16) short Vb[8192];      // V tile  [64][128], single
    __shared__ __align__(16) short Msk[2048];     // bf16 log2-bias, this b

    const int t = threadIdx.x;
    const int lane = t & 63, wid = t >> 6;
    const int quad = lane >> 4, l16 = lane & 15;
    const int qg = wid >> 1, kg = wid & 1;        // 2x2 hybrid split
    // XCD swizzle: XCD = id%8 owns bh in {xcd, xcd+8, xcd+16}
    const int id = blockIdx.x;
    const int idx = id >> 3;
    const int bh = (id & 7) + ((idx % 3) << 3);
    const int q0 = (idx / 3) << 6;
    const int b = bh / NH, h = bh - b * NH;
    const size_t hoff = (size_t)bh * NSEQ * HD;
    const short* qp = qb + hoff;     // [N][64]  (q pre-scaled by 0.125*log2e)
    const short* kp = kb + hoff;     // [N][64]
    const short* vp = vt + hoff;     // [64][N]  (keys permuted within 64)
    const int qrow4 = quad * 4;

    int rK[4], cK[4], dV[4], cV[4];
    #pragma unroll
    for (int j = 0; j < 4; ++j) {
        int o = wid * 4096 + j * 1024 + lane * 16;
        rK[j] = o >> 7;
        cK[j] = ((o >> 4) & 7) ^ (rK[j] & 7);
        dV[j] = o >> 8;
        cV[j] = ((o >> 4) & 15) ^ (dV[j] & 15);
    }
    const int r7 = l16 & 7;
    const int kc0 = ((quad     ^ r7) << 3);
    const int kc1 = (((quad+4) ^ r7) << 3);

    // Wave's 32 q rows: q0 + qg*32 + jq*16 + l16
    bf16x8 qf[2][2];
    {
        const short* qr = qp + (size_t)(q0 + qg*32 + l16) * HD + quad*8;
        qf[0][0] = *(const bf16x8*)qr;
        qf[0][1] = *(const bf16x8*)(qr + 32);
        qf[1][0] = *(const bf16x8*)(qr + 16*HD);
        qf[1][1] = *(const bf16x8*)(qr + 16*HD + 32);
    }

    const short one_ = (short)0x3F80;             // bf16 1.0
    const bf16x8 onesv = { one_, one_, one_, one_, one_, one_, one_, one_ };

    f32x4 o_acc[2][4] = {};
    f32x4 lacc[2] = {};
    bf16x8 pb[2][2];

    // Prologue: K tile 0 + mask row; __syncthreads drains vmcnt(0).
    STAGE_K(0, Kb[0]);
    gll16(maskb + b * NSEQ + t * 8, Msk + wid * 512);
    __syncthreads();

    for (int kt = 0; kt < NSEQ; kt += 256) {
        STAGE_V(kt);
        __builtin_amdgcn_sched_barrier(0);
        STAGE_K(kt + 128, Kb[1]);
        __builtin_amdgcn_sched_barrier(0);
        QKBODY(kt, Kb[0]);
        WAITV_BAR();              // A: V(kt) visible; K(kt+128) floats
        __builtin_amdgcn_s_setprio(1);
        PVBODY();
        __builtin_amdgcn_s_setprio(0);
        WAITK_BAR();              // B: K(kt+128) visible; Vb free

        STAGE_V(kt + 128);
        __builtin_amdgcn_sched_barrier(0);
        STAGE_K((kt + 256) & (NSEQ - 1), Kb[0]);
        __builtin_amdgcn_sched_barrier(0);
        QKBODY(kt + 128, Kb[1]);
        WAITV_BAR();              // A'
        __builtin_amdgcn_s_setprio(1);
        PVBODY();
        __builtin_amdgcn_s_setprio(0);
        WAITK_BAR();              // B'
    }

    // Epilogue: combine kg=0/kg=1 partials (disjoint key halves) via LDS.
    // Barrier B' carried vmcnt(0) -> wraparound staging landed; Kb is free.
    f32x4* red = (f32x4*)Kb;
    const int rbase = (qg*64 + lane) * 9;
    if (kg == 1) {
        #pragma unroll
        for (int jq = 0; jq < 2; ++jq)
            #pragma unroll
            for (int it = 0; it < 4; ++it)
                red[rbase + jq*4 + it] = o_acc[jq][it];
        f32x4 lv = { lacc[0][0], lacc[1][0], 0.f, 0.f };
        red[rbase + 8] = lv;
    }
    __syncthreads();
    if (kg == 0) {
        f32x4 lv = red[rbase + 8];
        const float inv0 = 1.0f / (lacc[0][0] + lv[0]);
        const float inv1 = 1.0f / (lacc[1][0] + lv[1]);
        #pragma unroll
        for (int jq = 0; jq < 2; ++jq) {
            const float inv = jq ? inv1 : inv0;
            const int tok = b * NSEQ + q0 + qg*32 + jq*16 + l16;
            short* dst = ao + (size_t)tok * CDIM + h * HD + qrow4;
            #pragma unroll
            for (int it = 0; it < 4; ++it) {
                f32x4 o_ = o_acc[jq][it];
                f32x4 r_ = red[rbase + jq*4 + it];
                short4v o = { f2b((o_[0] + r_[0]) * inv),
                              f2b((o_[1] + r_[1]) * inv),
                              f2b((o_[2] + r_[2]) * inv),
                              f2b((o_[3] + r_[3]) * inv) };
                *(short4v*)(dst + it*16) = o;
            }
        }
    }
}

// ---------------------------------------------------------------------------
// GEMM2: XCD-swizzled 1-D grid (192 = 8 x 24; m fastest within chunk).
// ---------------------------------------------------------------------------
__global__ __launch_bounds__(256) void gemm_proj(
    const short* __restrict__ A /*wpt[768][768]*/,
    const short* __restrict__ B /*ao [4096][768]*/,
    const float* __restrict__ bias, float* __restrict__ out)
{
    __shared__ short As[2 * 4096];
    __shared__ short Bs[2 * 4096];
    const int t = threadIdx.x;
    const int lane = t & 63, wid = t >> 6;
    const int quad = lane >> 4, l16 = lane & 15;
    const int wA = wid >> 1, wB = wid & 1;
    // XCD swizzle: 192 = 8 XCDs x 24.
    const int id = blockIdx.x;
    const int lin = (id & 7) * 24 + (id >> 3);
    const int n0 = (lin >> 5) * 128;      // 0..5
    const int m0 = (lin & 31) * 128;      // 0..31

    const int srow = wid * 16 + (lane >> 2), schunk = (lane & 3) * 8;
    const short* ag0 = A + (size_t)(n0 + srow) * CDIM + schunk;
    const short* ag1 = ag0 + (size_t)64 * CDIM;
    const short* bg0 = B + (size_t)(m0 + srow) * CDIM + schunk;
    const short* bg1 = bg0 + (size_t)64 * CDIM;

    f32x4 acc[4][4] = {};
    GSTAGE(0, 0);
    __syncthreads();
    int buf = 0;
    for (int k0 = 0; k0 < CDIM; k0 += 32) {
        if (k0 + 32 < CDIM) GSTAGE(k0 + 32, buf ^ 1);
        __builtin_amdgcn_sched_barrier(0);
        const short* As_ = As + buf * 4096;
        const short* Bs_ = Bs + buf * 4096;
        bf16x8 af[4], bf[4];
        #pragma unroll
        for (int i = 0; i < 4; ++i)
            af[i] = *(const bf16x8*)&As_[(wA*64 + i*16 + l16) * 32 + quad*8];
        #pragma unroll
        for (int j = 0; j < 4; ++j)
            bf[j] = *(const bf16x8*)&Bs_[(wB*64 + j*16 + l16) * 32 + quad*8];
        #pragma unroll
        for (int i = 0; i < 4; ++i)
            #pragma unroll
            for (int j = 0; j < 4; ++j)
                acc[i][j] = MFMA16(af[i], bf[j], acc[i][j]);
        __syncthreads();          // stage(next) had the whole MFMA phase
        buf ^= 1;
    }

    #pragma unroll
    for (int i = 0; i < 4; ++i) {
        int col0 = n0 + wA*64 + i*16 + quad*4;
        float4 bias4 = *(const float4*)&bias[col0];
        #pragma unroll
        for (int j = 0; j < 4; ++j) {
            int tok = m0 + wB*64 + j*16 + l16;
            float4 o = { acc[i][j][0] + bias4.x, acc[i][j][1] + bias4.y,
                         acc[i][j][2] + bias4.z, acc[i][j][3] + bias4.w };
            *(float4*)(out + (size_t)tok * CDIM + col0) = o;
        }
    }
}

extern "C" void kernel_launch(void* const* d_in, const int* in_sizes, int n_in,
                              void* d_out, int out_size, void* d_ws, size_t ws_size,
                              hipStream_t stream)
{
    const float* x      = (const float*)d_in[0];
    const int*   mask   = (const int*)d_in[1];
    const float* w_qkv  = (const float*)d_in[2];
    const float* w_proj = (const float*)d_in[3];
    const float* b_proj = (const float*)d_in[4];
    float* out = (float*)d_out;

    const size_t SZ = (size_t)NTOK * CDIM;       // 3,145,728
    short* xb  = (short*)d_ws;                   // [4096][768]
    short* wqt = xb  + SZ;                       // [2304][768]
    short* wpt = wqt + (size_t)QKV_COLS * CDIM;  // [768][768]
    short* qb  = wpt + (size_t)CDIM * CDIM;      // [BH][N][64]  (pre-scaled q)
    short* kb  = qb  + SZ;                       // [BH][N][64]
    short* vt  = kb  + SZ;                       // [BH][64][N]  (key-permuted)
    short* ao  = vt  + SZ;                       // [4096][768]
    short* maskb = ao + SZ;                      // [B][N] bf16 log2-bias

    dim3 blk(256);
    prep_kernel<<<dim3(5378), blk, 0, stream>>>(x, w_qkv, w_proj, mask,
                                                xb, wqt, wpt, maskb);
    gemm_qkv<<<dim3(576), blk, 0, stream>>>(wqt, xb, qb, kb, vt);
    attn_kernel<<<dim3(NBLK), blk, 0, stream>>>(qb, kb, vt, maskb, ao);
    gemm_proj<<<dim3(192), blk, 0, stream>>>(wpt, ao, b_proj, out);
}